// Round 1
// baseline (913.149 us; speedup 1.0000x reference)
//
#include <hip/hip_runtime.h>
#include <math.h>

// Problem constants (folded from reference):
//   N=16, C=64, T=30, H=64, W=44, OUT_H=16, OUT_W=20
//   atten_in_t=12, atten_in_h=32, atten_in_w=40, aout_h=16 (== OUT_H -> no pad)
//   anchor_t=15, anchor_x=22, anchor_y=24
#define NN 16
#define CC 64
#define TT 30
#define HH 64
#define WW 44
#define OUTH 16
#define OUTW 20
#define HW 320   // OUTH*OUTW

// Workspace layout (floats)
#define FX_OFF    0                       // [16][20][44] = 14080
#define FY_OFF    14080                   // [16][16][64] = 16384
#define IDX0_OFF  30464                   // int[480]
#define IDX1_OFF  30944                   // int[480]
#define TW0_OFF   31424                   // float[480]
#define TW1_OFF   31904                   // float[480]
#define GAM_OFF   32384                   // float[16]
#define G_OFF     32400                   // [16][64][30][320] = 9830400

// ---------------------------------------------------------------------------
// Kernel 1: per-n MLP -> attention params -> normalized Fx/Fy, time weights
// ---------------------------------------------------------------------------
__global__ __launch_bounds__(64) void params_kernel(
    const float* __restrict__ param_x, const float* __restrict__ W1,
    const float* __restrict__ b1, const float* __restrict__ W2,
    const float* __restrict__ b2, float* __restrict__ ws,
    float* __restrict__ params_out) {
  int n = blockIdx.x;
  int tid = threadIdx.x;  // 64 threads
  __shared__ float px[64];
  __shared__ float hid[32];
  __shared__ float pv[7];

  px[tid] = param_x[n * 64 + tid];
  __syncthreads();
  if (tid < 32) {
    float s = b1[tid];
    #pragma unroll
    for (int k = 0; k < 64; ++k) s += px[k] * W1[k * 32 + tid];
    hid[tid] = tanhf(s);
  }
  __syncthreads();
  if (tid < 7) {
    float s = b2[tid];
    #pragma unroll
    for (int j = 0; j < 32; ++j) s += hid[j] * W2[j * 7 + tid];
    pv[tid] = s;
  }
  __syncthreads();

  // Derived scalars (all threads redundantly)
  float dt      = tanhf(pv[0]) * 6.0f  + 15.0f;  // atten_in_t/2, anchor_t
  float dx      = tanhf(pv[1]) * 20.0f + 22.0f;  // atten_in_w/2, anchor_x
  float dy      = tanhf(pv[2]) * 16.0f + 24.0f;  // atten_in_h/2, anchor_y
  float sigma2  = expf(pv[3]);
  float delta_t = expf(pv[4]) * 0.4f;
  float delta   = expf(pv[5]) * (10.0f / 11.0f);
  float gamma   = 1.0f / (1.0f + expf(-pv[6]));
  float inv2s2  = 1.0f / (2.0f * sigma2);

  // Fx rows: q in [0,20), 44 wide, row-normalized
  if (tid < 20) {
    float mu = dx + ((float)tid - 10.0f) * delta;
    float vals[44];
    float s = 0.0f;
    #pragma unroll
    for (int w = 0; w < 44; ++w) {
      float d = (float)w - mu;
      float e = expf(-d * d * inv2s2);
      vals[w] = e; s += e;
    }
    float inv = 1.0f / fmaxf(s, 1e-8f);
    float* Fx = ws + FX_OFF + n * (20 * 44) + tid * 44;
    #pragma unroll
    for (int w = 0; w < 44; ++w) Fx[w] = vals[w] * inv;
  }
  // Fy rows: p in [0,16), 64 wide, row-normalized
  if (tid < 16) {
    float mu = dy + ((float)tid - 8.0f) * delta;
    float vals[64];
    float s = 0.0f;
    #pragma unroll
    for (int h = 0; h < 64; ++h) {
      float d = (float)h - mu;
      float e = expf(-d * d * inv2s2);
      vals[h] = e; s += e;
    }
    float inv = 1.0f / fmaxf(s, 1e-8f);
    float* Fy = ws + FY_OFF + n * (16 * 64) + tid * 64;
    #pragma unroll
    for (int h = 0; h < 64; ++h) Fy[h] = vals[h] * inv;
  }
  // Time-resample weights: t' in [0,30)
  if (tid < 30) {
    float mu = dt + ((float)tid - 15.0f) * delta_t;
    float i0f = floorf(mu);
    float frac = mu - i0f;
    int i0 = (int)i0f;
    int i1 = i0 + 1;
    float w0 = (i0 >= 0 && i0 < TT) ? (1.0f - frac) : 0.0f;
    float w1 = (i1 >= 0 && i1 < TT) ? frac : 0.0f;
    ((int*)(ws + IDX0_OFF))[n * TT + tid] = min(max(i0, 0), TT - 1);
    ((int*)(ws + IDX1_OFF))[n * TT + tid] = min(max(i1, 0), TT - 1);
    ws[TW0_OFF + n * TT + tid] = w0;
    ws[TW1_OFF + n * TT + tid] = w1;
  }
  if (tid == 0) {
    ws[GAM_OFF + n] = gamma;
    params_out[0 * NN + n] = dt;
    params_out[1 * NN + n] = dx;
    params_out[2 * NN + n] = dy;
    params_out[3 * NN + n] = sigma2;
    params_out[4 * NN + n] = delta;
    params_out[5 * NN + n] = delta_t;
    params_out[6 * NN + n] = gamma;
  }
}

// ---------------------------------------------------------------------------
// Kernel 2: per-(n,c,t) separable spatial attention: g = Fy * (x * Fx^T)
// ---------------------------------------------------------------------------
__global__ __launch_bounds__(256) void spatial_kernel(
    const float* __restrict__ x, const float* __restrict__ ws,
    float* __restrict__ g) {
  int b = blockIdx.x;          // b = (n*64 + c)*30 + t
  int n = b / (CC * TT);
  __shared__ float sx[HH * WW];        // 64x44
  __shared__ float sFx[20 * 45];       // padded stride 45 (conflict-free)
  __shared__ float sFy[16 * 65];       // padded stride 65
  __shared__ float st1[HH * 21];       // 64x20, padded stride 21
  int tid = threadIdx.x;

  const float* xs = x + (size_t)b * (HH * WW);
  for (int i = tid; i < HH * WW; i += 256) sx[i] = xs[i];
  const float* Fx = ws + FX_OFF + n * (20 * 44);
  for (int i = tid; i < 20 * 44; i += 256) sFx[(i / 44) * 45 + (i % 44)] = Fx[i];
  const float* Fy = ws + FY_OFF + n * (16 * 64);
  for (int i = tid; i < 16 * 64; i += 256) sFy[(i / 64) * 65 + (i % 64)] = Fy[i];
  __syncthreads();

  // t1[h][q] = sum_w sx[h][w] * Fx[q][w]
  for (int i = tid; i < HH * OUTW; i += 256) {
    int h = i / OUTW, q = i % OUTW;
    float s = 0.0f;
    #pragma unroll
    for (int w = 0; w < WW; ++w) s += sx[h * WW + w] * sFx[q * 45 + w];
    st1[h * 21 + q] = s;
  }
  __syncthreads();

  // g[p][q] = sum_h Fy[p][h] * t1[h][q]
  float* gout = g + (size_t)b * HW;
  for (int i = tid; i < HW; i += 256) {
    int p = i / OUTW, q = i % OUTW;
    float s = 0.0f;
    #pragma unroll
    for (int h = 0; h < HH; ++h) s += sFy[p * 65 + h] * st1[h * 21 + q];
    gout[i] = s;
  }
}

// ---------------------------------------------------------------------------
// Kernel 3: per-(n,t') time resample + gamma + channel mix (Wf) + bias
// ---------------------------------------------------------------------------
__global__ __launch_bounds__(256) void output_kernel(
    const float* __restrict__ g, const float* __restrict__ ws,
    const float* __restrict__ Wf, const float* __restrict__ bf,
    float* __restrict__ out) {
  int b = blockIdx.x;     // n*30 + t'
  int tp = b % TT;
  int n = b / TT;
  __shared__ float sWf[CC * CC];       // 16 KB
  __shared__ float smix[CC * HW];      // 80 KB
  int tid = threadIdx.x;

  for (int i = tid; i < CC * CC; i += 256) sWf[i] = Wf[i];
  int i0 = ((const int*)(ws + IDX0_OFF))[n * TT + tp];
  int i1 = ((const int*)(ws + IDX1_OFF))[n * TT + tp];
  float w0 = ws[TW0_OFF + n * TT + tp];
  float w1 = ws[TW1_OFF + n * TT + tp];
  float gamma = ws[GAM_OFF + n];

  for (int i = tid; i < CC * HW; i += 256) {
    int c = i / HW, hw = i % HW;
    size_t base = ((size_t)(n * CC + c) * TT);
    float g0 = g[(base + i0) * HW + hw];
    float g1 = g[(base + i1) * HW + hw];
    smix[i] = gamma * (w0 * g0 + w1 * g1);
  }
  __syncthreads();

  for (int i = tid; i < CC * HW; i += 256) {
    int oc = i / HW, hw = i % HW;
    float s = bf[oc];
    #pragma unroll
    for (int c = 0; c < CC; ++c) s += sWf[oc * CC + c] * smix[c * HW + hw];
    out[(((size_t)n * CC + oc) * TT + tp) * HW + hw] = s;
  }
}

// ---------------------------------------------------------------------------
extern "C" void kernel_launch(void* const* d_in, const int* in_sizes, int n_in,
                              void* d_out, int out_size, void* d_ws,
                              size_t ws_size, hipStream_t stream) {
  const float* x       = (const float*)d_in[0];
  const float* param_x = (const float*)d_in[1];
  const float* W1      = (const float*)d_in[2];
  const float* b1      = (const float*)d_in[3];
  const float* W2      = (const float*)d_in[4];
  const float* b2      = (const float*)d_in[5];
  const float* Wf      = (const float*)d_in[6];
  const float* bf      = (const float*)d_in[7];
  float* out = (float*)d_out;
  float* ws  = (float*)d_ws;
  float* params_out = out + (size_t)NN * CC * TT * HW;  // 9830400

  params_kernel<<<NN, 64, 0, stream>>>(param_x, W1, b1, W2, b2, ws, params_out);
  spatial_kernel<<<NN * CC * TT, 256, 0, stream>>>(x, ws, ws + G_OFF);
  output_kernel<<<NN * TT, 256, 0, stream>>>(ws + G_OFF, ws, Wf, bf, out);
}

// Round 2
// 549.558 us; speedup vs baseline: 1.6616x; 1.6616x over previous
//
#include <hip/hip_runtime.h>
#include <math.h>

// Problem constants (folded from reference):
//   N=16, C=64, T=30, H=64, W=44, OUT_H=16, OUT_W=20
//   atten_in_t=12, atten_in_h=32, atten_in_w=40, aout_h=16 (== OUT_H -> no pad)
//   anchor_t=15, anchor_x=22, anchor_y=24
#define NN 16
#define CC 64
#define TT 30
#define HH 64
#define WW 44
#define OUTH 16
#define OUTW 20
#define HW 320   // OUTH*OUTW

// Workspace layout (floats)
#define FX_OFF    0                       // [16][20][44] = 14080
#define FY_OFF    14080                   // [16][16][64] = 16384
#define IDX0_OFF  30464                   // int[480]
#define IDX1_OFF  30944                   // int[480]
#define TW0_OFF   31424                   // float[480]
#define TW1_OFF   31904                   // float[480]
#define GAM_OFF   32384                   // float[16]
#define G_OFF     32400                   // [16][64][30][320] = 9830400

// ---------------------------------------------------------------------------
// Kernel 1: per-n MLP -> attention params -> normalized Fx/Fy, time weights
// ---------------------------------------------------------------------------
__global__ __launch_bounds__(64) void params_kernel(
    const float* __restrict__ param_x, const float* __restrict__ W1,
    const float* __restrict__ b1, const float* __restrict__ W2,
    const float* __restrict__ b2, float* __restrict__ ws,
    float* __restrict__ params_out) {
  int n = blockIdx.x;
  int tid = threadIdx.x;  // 64 threads
  __shared__ float px[64];
  __shared__ float hid[32];
  __shared__ float pv[7];

  px[tid] = param_x[n * 64 + tid];
  __syncthreads();
  if (tid < 32) {
    float s = b1[tid];
    #pragma unroll
    for (int k = 0; k < 64; ++k) s += px[k] * W1[k * 32 + tid];
    hid[tid] = tanhf(s);
  }
  __syncthreads();
  if (tid < 7) {
    float s = b2[tid];
    #pragma unroll
    for (int j = 0; j < 32; ++j) s += hid[j] * W2[j * 7 + tid];
    pv[tid] = s;
  }
  __syncthreads();

  float dt      = tanhf(pv[0]) * 6.0f  + 15.0f;
  float dx      = tanhf(pv[1]) * 20.0f + 22.0f;
  float dy      = tanhf(pv[2]) * 16.0f + 24.0f;
  float sigma2  = expf(pv[3]);
  float delta_t = expf(pv[4]) * 0.4f;
  float delta   = expf(pv[5]) * (10.0f / 11.0f);
  float gamma   = 1.0f / (1.0f + expf(-pv[6]));
  float inv2s2  = 1.0f / (2.0f * sigma2);

  if (tid < 20) {
    float mu = dx + ((float)tid - 10.0f) * delta;
    float vals[44];
    float s = 0.0f;
    #pragma unroll
    for (int w = 0; w < 44; ++w) {
      float d = (float)w - mu;
      float e = expf(-d * d * inv2s2);
      vals[w] = e; s += e;
    }
    float inv = 1.0f / fmaxf(s, 1e-8f);
    float* Fx = ws + FX_OFF + n * (20 * 44) + tid * 44;
    #pragma unroll
    for (int w = 0; w < 44; ++w) Fx[w] = vals[w] * inv;
  }
  if (tid < 16) {
    float mu = dy + ((float)tid - 8.0f) * delta;
    float vals[64];
    float s = 0.0f;
    #pragma unroll
    for (int h = 0; h < 64; ++h) {
      float d = (float)h - mu;
      float e = expf(-d * d * inv2s2);
      vals[h] = e; s += e;
    }
    float inv = 1.0f / fmaxf(s, 1e-8f);
    float* Fy = ws + FY_OFF + n * (16 * 64) + tid * 64;
    #pragma unroll
    for (int h = 0; h < 64; ++h) Fy[h] = vals[h] * inv;
  }
  if (tid < 30) {
    float mu = dt + ((float)tid - 15.0f) * delta_t;
    float i0f = floorf(mu);
    float frac = mu - i0f;
    int i0 = (int)i0f;
    int i1 = i0 + 1;
    float w0 = (i0 >= 0 && i0 < TT) ? (1.0f - frac) : 0.0f;
    float w1 = (i1 >= 0 && i1 < TT) ? frac : 0.0f;
    ((int*)(ws + IDX0_OFF))[n * TT + tid] = min(max(i0, 0), TT - 1);
    ((int*)(ws + IDX1_OFF))[n * TT + tid] = min(max(i1, 0), TT - 1);
    ws[TW0_OFF + n * TT + tid] = w0;
    ws[TW1_OFF + n * TT + tid] = w1;
  }
  if (tid == 0) {
    ws[GAM_OFF + n] = gamma;
    params_out[0 * NN + n] = dt;
    params_out[1 * NN + n] = dx;
    params_out[2 * NN + n] = dy;
    params_out[3 * NN + n] = sigma2;
    params_out[4 * NN + n] = delta;
    params_out[5 * NN + n] = delta_t;
    params_out[6 * NN + n] = gamma;
  }
}

// ---------------------------------------------------------------------------
// Kernel 2 v2: block = (n, t, c-quad). Thread owns x row in registers.
// Stage 1: t1[h][q] = sum_w x[h][w]*Fx[q][w]  (x in VGPRs, Fx via SMEM s_load)
// Stage 2: g[p][q]  = sum_h Fy[p][h]*t1[h][q] (t1/Fy in LDS, b128 broadcast)
// ---------------------------------------------------------------------------
__global__ __launch_bounds__(256) void spatial_kernel(
    const float* __restrict__ x, const float* __restrict__ fxbuf,
    const float* __restrict__ fybuf, float* __restrict__ g) {
  int b = blockIdx.x;                 // 0 .. 16*30*16-1
  int n  = b / (TT * 16);
  int r  = b % (TT * 16);
  int t  = r / 16;
  int c0 = (r % 16) * 4;

  int tid  = threadIdx.x;
  int cl   = tid >> 6;        // 0..3
  int lane = tid & 63;

  __shared__ float st1[4 * 20 * 68];  // [cl][q][h], stride 68 (bank-spread)
  __shared__ float sFy[16 * 68];      // [p][h], stride 68

  // Load Fy into LDS (1024 floats)
  {
    const float* Fy = fybuf + n * (16 * 64);
    #pragma unroll
    for (int i = tid; i < 16 * 64; i += 256) {
      int p = i >> 6, h = i & 63;
      sFy[p * 68 + h] = Fy[i];
    }
  }

  // ---- Stage 1: thread handles (c0+cl, h=lane), x row in registers ----
  int c = c0 + cl;
  const float* xs = x + ((((size_t)n * CC + c) * TT + t) * HH + lane) * WW;
  float xrow[44];
  {
    const float4* xp = (const float4*)xs;
    #pragma unroll
    for (int i = 0; i < 11; ++i) {
      float4 v = xp[i];
      xrow[4 * i + 0] = v.x; xrow[4 * i + 1] = v.y;
      xrow[4 * i + 2] = v.z; xrow[4 * i + 3] = v.w;
    }
  }
  const float* fx = fxbuf + n * (20 * 44);  // wave-uniform -> s_load
  float acc[20];
  #pragma unroll
  for (int q = 0; q < 20; ++q) {
    float s = 0.0f;
    #pragma unroll
    for (int w = 0; w < 44; ++w) s = fmaf(xrow[w], fx[q * 44 + w], s);
    acc[q] = s;
  }
  #pragma unroll
  for (int q = 0; q < 20; ++q) st1[(cl * 20 + q) * 68 + lane] = acc[q];
  __syncthreads();

  // ---- Stage 2: thread = (cl, p = lane>>2, qg = lane&3), 5 q's per thread
  int p  = lane >> 2;
  int qg = lane & 3;
  float o[5] = {0.f, 0.f, 0.f, 0.f, 0.f};
  #pragma unroll
  for (int hc = 0; hc < 16; ++hc) {
    float4 fy = *(const float4*)&sFy[p * 68 + hc * 4];
    #pragma unroll
    for (int j = 0; j < 5; ++j) {
      int q = qg * 5 + j;
      float4 tv = *(const float4*)&st1[(cl * 20 + q) * 68 + hc * 4];
      o[j] = fmaf(fy.x, tv.x, fmaf(fy.y, tv.y, fmaf(fy.z, tv.z, fmaf(fy.w, tv.w, o[j]))));
    }
  }
  float* gout = g + ((size_t)((n * CC + c) * TT + t)) * HW + p * OUTW + qg * 5;
  #pragma unroll
  for (int j = 0; j < 5; ++j) gout[j] = o[j];
}

// ---------------------------------------------------------------------------
// Kernel 3 v2: block = (n, t', hw-half). Register-tiled 8oc x 5hw micro-GEMM.
// ---------------------------------------------------------------------------
__global__ __launch_bounds__(256) void output_kernel(
    const float* __restrict__ g, const float* __restrict__ ws,
    const float* __restrict__ Wf, const float* __restrict__ bf,
    float* __restrict__ out) {
  int b = blockIdx.x;             // 0 .. 16*30*2-1
  int n    = b / (TT * 2);
  int r    = b % (TT * 2);
  int tp   = r >> 1;
  int hw0  = (r & 1) * 160;
  int tid  = threadIdx.x;

  __shared__ float sWfT[64 * 65];   // [c][oc], pad 65 (16.6 KB)
  __shared__ float smix[64 * 160];  // [c][hw-half]   (40.96 KB)

  // Wf transposed into LDS
  #pragma unroll
  for (int i = tid; i < 64 * 64; i += 256) {
    int oc = i >> 6, c = i & 63;
    sWfT[c * 65 + oc] = Wf[i];
  }

  int i0 = ((const int*)(ws + IDX0_OFF))[n * TT + tp];
  int i1 = ((const int*)(ws + IDX1_OFF))[n * TT + tp];
  float w0 = ws[TW0_OFF + n * TT + tp];
  float w1 = ws[TW1_OFF + n * TT + tp];
  float gamma = ws[GAM_OFF + n];

  // time-resample + gamma into LDS
  #pragma unroll
  for (int i = tid; i < 64 * 160; i += 256) {
    int c = i / 160, hwl = i % 160;
    size_t base = (size_t)(n * CC + c) * TT;
    float g0 = g[(base + i0) * HW + hw0 + hwl];
    float g1 = g[(base + i1) * HW + hw0 + hwl];
    smix[i] = gamma * (w0 * g0 + w1 * g1);
  }
  __syncthreads();

  // micro-GEMM: thread tile 8 oc x 5 hw
  int ocg = tid >> 5;           // 0..7  -> oc0 = ocg*8
  int hwg = tid & 31;           // 0..31 -> hwl0 = hwg*5
  int oc0 = ocg * 8;
  int hwl0 = hwg * 5;
  float acc[8][5];
  #pragma unroll
  for (int u = 0; u < 8; ++u)
    #pragma unroll
    for (int j = 0; j < 5; ++j) acc[u][j] = 0.0f;

  #pragma unroll 4
  for (int c = 0; c < 64; ++c) {
    float4 wv0 = *(const float4*)&sWfT[c * 65 + oc0];
    float4 wv1 = *(const float4*)&sWfT[c * 65 + oc0 + 4];
    float m[5];
    #pragma unroll
    for (int j = 0; j < 5; ++j) m[j] = smix[c * 160 + hwl0 + j];
    float wv[8] = {wv0.x, wv0.y, wv0.z, wv0.w, wv1.x, wv1.y, wv1.z, wv1.w};
    #pragma unroll
    for (int u = 0; u < 8; ++u)
      #pragma unroll
      for (int j = 0; j < 5; ++j) acc[u][j] = fmaf(wv[u], m[j], acc[u][j]);
  }

  #pragma unroll
  for (int u = 0; u < 8; ++u) {
    int oc = oc0 + u;
    float bias = bf[oc];
    float* op = out + (((size_t)n * CC + oc) * TT + tp) * HW + hw0 + hwl0;
    #pragma unroll
    for (int j = 0; j < 5; ++j) op[j] = acc[u][j] + bias;
  }
}

// ---------------------------------------------------------------------------
extern "C" void kernel_launch(void* const* d_in, const int* in_sizes, int n_in,
                              void* d_out, int out_size, void* d_ws,
                              size_t ws_size, hipStream_t stream) {
  const float* x       = (const float*)d_in[0];
  const float* param_x = (const float*)d_in[1];
  const float* W1      = (const float*)d_in[2];
  const float* b1      = (const float*)d_in[3];
  const float* W2      = (const float*)d_in[4];
  const float* b2      = (const float*)d_in[5];
  const float* Wf      = (const float*)d_in[6];
  const float* bf      = (const float*)d_in[7];
  float* out = (float*)d_out;
  float* ws  = (float*)d_ws;
  float* params_out = out + (size_t)NN * CC * TT * HW;  // 9830400

  params_kernel<<<NN, 64, 0, stream>>>(param_x, W1, b1, W2, b2, ws, params_out);
  spatial_kernel<<<NN * TT * 16, 256, 0, stream>>>(
      x, ws + FX_OFF, ws + FY_OFF, ws + G_OFF);
  output_kernel<<<NN * TT * 2, 256, 0, stream>>>(ws + G_OFF, ws, Wf, bf, out);
}